// Round 4
// baseline (421.642 us; speedup 1.0000x reference)
//
#include <hip/hip_runtime.h>

#define N_NODES 100000
#define N_EDGES 1000000

typedef __attribute__((ext_vector_type(8))) short bf16x8;
typedef __attribute__((ext_vector_type(4))) float f32x4;

static __device__ __forceinline__ short f2bf(float f) {
    unsigned u = __float_as_uint(f);
    u = (u + 0x7fffu + ((u >> 16) & 1u)) >> 16;
    return (short)u;
}
static __device__ __forceinline__ float bf2f(unsigned short s) {
    return __uint_as_float(((unsigned)s) << 16);
}
static __device__ __forceinline__ float lrelu(float x) {
    return fmaxf(x, 0.01f * x);
}

// ---------------------------------------------------------------------------
// Precompute: P/Q bf16, gather-swizzled layout (unchanged from R3):
//   ch=64w+16mtl+4q+r stored at row pos q*32 + 16*(w&1) + 4*mtl + r.
// New: x-tile staged in LDS as bf16 ONCE per block (was 4x redundant global),
//      stores coalesced to 2x16B per lane (was 4x8B scattered).
// ---------------------------------------------------------------------------
__global__ __launch_bounds__(256, 4) void precompute_mfma(
    const float* __restrict__ x, const float* __restrict__ W1,
    const float* __restrict__ b1, unsigned short* __restrict__ Pb,
    unsigned short* __restrict__ Qb)
{
    __shared__ unsigned short xbf[16][136];   // padded: stride 272B (17x16B)
    const int t    = threadIdx.x;
    const int lane = t & 63;
    const int w    = t >> 6;
    const int q    = lane >> 4;
    const int n15  = lane & 15;
    const int chb  = 64 * w;

    bf16x8 afrag[4][4];
    #pragma unroll
    for (int mtl = 0; mtl < 4; ++mtl) {
        const int ch = chb + 16 * mtl + n15;
        const float* wcol = (ch < 128) ? (W1 + ch) : (W1 + 128 * 128 + (ch - 128));
        #pragma unroll
        for (int ks = 0; ks < 4; ++ks)
            #pragma unroll
            for (int j = 0; j < 8; ++j)
                afrag[mtl][ks][j] = f2bf(wcol[(size_t)(32 * ks + 8 * q + j) * 128]);
    }
    float b1r[16];
    #pragma unroll
    for (int mtl = 0; mtl < 4; ++mtl)
        #pragma unroll
        for (int r = 0; r < 4; ++r) {
            const int ch = chb + 16 * mtl + 4 * q + r;
            b1r[mtl * 4 + r] = (ch < 128) ? b1[ch] : 0.0f;
        }

    unsigned short* tbase = (w < 2) ? Pb : Qb;
    const int half = (w & 1);   // 16-short offset within the q*32 group

    const int xnode = t >> 4;         // staging: node 0..15
    const int xcol  = (t & 15) * 8;   // 8 floats per thread

    for (int tile = blockIdx.x; tile < N_NODES / 16; tile += gridDim.x) {
        const int n0 = tile * 16;

        // stage x tile -> bf16 LDS (each thread: 8 floats, one 16B LDS write)
        {
            const float* src = x + (size_t)(n0 + xnode) * 128 + xcol;
            f32x4 va = *(const f32x4*)src;
            f32x4 vb = *(const f32x4*)(src + 4);
            bf16x8 pk;
            #pragma unroll
            for (int j = 0; j < 4; ++j) { pk[j] = f2bf(va[j]); pk[4 + j] = f2bf(vb[j]); }
            *(bf16x8*)&xbf[xnode][xcol] = pk;
        }
        __syncthreads();

        unsigned short hs16[16];
        #pragma unroll
        for (int mtl = 0; mtl < 4; ++mtl) {
            f32x4 acc = {0.f, 0.f, 0.f, 0.f};
            #pragma unroll
            for (int ks = 0; ks < 4; ++ks) {
                bf16x8 bfr = *(const bf16x8*)&xbf[n15][32 * ks + 8 * q];
                acc = __builtin_amdgcn_mfma_f32_16x16x32_bf16(afrag[mtl][ks], bfr, acc, 0, 0, 0);
            }
            #pragma unroll
            for (int r = 0; r < 4; ++r)
                hs16[mtl * 4 + r] = (unsigned short)f2bf(acc[r] + b1r[mtl * 4 + r]);
        }
        // coalesced 32B store per lane: row pos q*32 + half*16 .. +16
        unsigned short* dst = tbase + (size_t)(n0 + n15) * 128 + q * 32 + half * 16;
        *(bf16x8*)dst       = *(bf16x8*)&hs16[0];
        *(bf16x8*)(dst + 8) = *(bf16x8*)&hs16[8];
        __syncthreads();
    }
}

// ---------------------------------------------------------------------------
// Edge kernel, software-pipelined, wave-private tiles.
// R4: W2^T fragment table moved to LDS (frees 64 VGPRs -> 4 waves/SIMD).
// ---------------------------------------------------------------------------
__global__ __launch_bounds__(256, 4) void edge_mfma(
    const int* __restrict__ ei, const float* __restrict__ ef,
    const float* __restrict__ W1, const float* __restrict__ W2,
    const float* __restrict__ b2, const float* __restrict__ W3,
    const float* __restrict__ b3, const unsigned short* __restrict__ Pb,
    const unsigned short* __restrict__ Qb, float* __restrict__ out)
{
    __shared__ unsigned short w2t[16 * 64 * 8];        // 16 KB: [frag][lane][8]
    __shared__ unsigned short hbuf[4][16 * 136 + 8];   // 17.4 KB
    const int t    = threadIdx.x;
    const int lane = t & 63;
    const int w    = t >> 6;
    const int q    = lane >> 4;
    const int n15  = lane & 15;
    unsigned short* hb = &hbuf[w][0];

    // persistent A-frags: W1c^T (32 VGPRs)
    bf16x8 a1[8];
    #pragma unroll
    for (int mt = 0; mt < 8; ++mt)
        #pragma unroll
        for (int j = 0; j < 8; ++j)
            a1[mt][j] = f2bf(W1[(size_t)(256 + 8 * q + j) * 128 + 16 * mt + n15]);

    // build W2^T fragment table in LDS: wave w -> mt2=w, ks=0..3
    #pragma unroll
    for (int ks = 0; ks < 4; ++ks) {
        bf16x8 v;
        #pragma unroll
        for (int j = 0; j < 8; ++j)
            v[j] = f2bf(W2[(size_t)(32 * ks + 8 * q + j) * 64 + 16 * w + n15]);
        *(bf16x8*)&w2t[((w * 4 + ks) * 64 + lane) * 8] = v;
    }

    unsigned b2w3[16];
    #pragma unroll
    for (int mt2 = 0; mt2 < 4; ++mt2)
        #pragma unroll
        for (int r = 0; r < 4; ++r) {
            const int ch = 16 * mt2 + 4 * q + r;
            b2w3[mt2 * 4 + r] = (unsigned)(unsigned short)f2bf(b2[ch])
                              | ((unsigned)(unsigned short)f2bf(W3[ch]) << 16);
        }
    const float b3v = b3[0];
    __syncthreads();   // w2t ready; no further block syncs

    const int nTiles  = N_EDGES / 16;
    const int wid     = blockIdx.x * 4 + w;
    const int wstride = gridDim.x * 4;

    // ---- prologue: prefetch tile 0 ----
    int tile = wid;
    int e0   = tile * 16;
    int oi = ei[e0 + n15];
    int di = ei[N_EDGES + e0 + n15];
    f32x4 ea = *(const f32x4*)(ef + (size_t)(e0 + n15) * 32 + 8 * q);
    f32x4 eb = *(const f32x4*)(ef + (size_t)(e0 + n15) * 32 + 8 * q + 4);
    bf16x8 pvb[4], qvb[4];
    {
        const unsigned short* prow = Pb + (size_t)oi * 128 + q * 32;
        const unsigned short* qrow = Qb + (size_t)di * 128 + q * 32;
        #pragma unroll
        for (int c = 0; c < 4; ++c) {
            pvb[c] = *(const bf16x8*)(prow + 8 * c);
            qvb[c] = *(const bf16x8*)(qrow + 8 * c);
        }
    }

    while (true) {
        const int  next = tile + wstride;
        const bool have = next < nTiles;

        bf16x8 bef;
        #pragma unroll
        for (int j = 0; j < 4; ++j) { bef[j] = f2bf(ea[j]); bef[4 + j] = f2bf(eb[j]); }

        // prefetch next indices + edge features
        int noi = 0, ndi = 0;
        f32x4 nea = ea, neb = eb;
        if (have) {
            const int ne0 = next * 16;
            noi = ei[ne0 + n15];
            ndi = ei[N_EDGES + ne0 + n15];
            nea = *(const f32x4*)(ef + (size_t)(ne0 + n15) * 32 + 8 * q);
            neb = *(const f32x4*)(ef + (size_t)(ne0 + n15) * 32 + 8 * q + 4);
        }

        // ---- phase 1: 8 MFMA + epilogue -> LDS bf16 ----
        #pragma unroll
        for (int mt = 0; mt < 8; ++mt) {
            f32x4 z = {0.f, 0.f, 0.f, 0.f};
            f32x4 h = __builtin_amdgcn_mfma_f32_16x16x32_bf16(a1[mt], bef, z, 0, 0, 0);
            const int c = mt >> 1, off = (mt & 1) * 4;
            unsigned short hs[4];
            #pragma unroll
            for (int r = 0; r < 4; ++r) {
                float v = h[r] + bf2f((unsigned short)pvb[c][off + r])
                               + bf2f((unsigned short)qvb[c][off + r]);
                hs[r] = (unsigned short)f2bf(lrelu(v));
            }
            unsigned* d = (unsigned*)&hb[n15 * 136 + 16 * mt + 4 * q];
            d[0] = (unsigned)hs[0] | ((unsigned)hs[1] << 16);
            d[1] = (unsigned)hs[2] | ((unsigned)hs[3] << 16);
        }

        // pvb/qvb dead: issue next tile's gathers
        if (have) {
            const unsigned short* prow = Pb + (size_t)noi * 128 + q * 32;
            const unsigned short* qrow = Qb + (size_t)ndi * 128 + q * 32;
            #pragma unroll
            for (int c = 0; c < 4; ++c) {
                pvb[c] = *(const bf16x8*)(prow + 8 * c);
                qvb[c] = *(const bf16x8*)(qrow + 8 * c);
            }
        }

        __asm__ __volatile__("s_waitcnt lgkmcnt(0)" ::: "memory");

        // ---- phase 2: 16 MFMA, W2 frags streamed from LDS ----
        f32x4 acc2[4] = {{0.f,0.f,0.f,0.f},{0.f,0.f,0.f,0.f},{0.f,0.f,0.f,0.f},{0.f,0.f,0.f,0.f}};
        #pragma unroll
        for (int ks = 0; ks < 4; ++ks) {
            bf16x8 hfrag = *(const bf16x8*)&hb[n15 * 136 + 32 * ks + 8 * q];
            #pragma unroll
            for (int mt2 = 0; mt2 < 4; ++mt2) {
                bf16x8 a2f = *(const bf16x8*)&w2t[((mt2 * 4 + ks) * 64 + lane) * 8];
                acc2[mt2] = __builtin_amdgcn_mfma_f32_16x16x32_bf16(a2f, hfrag, acc2[mt2], 0, 0, 0);
            }
        }

        // ---- phase 3 ----
        float s = 0.0f;
        #pragma unroll
        for (int mt2 = 0; mt2 < 4; ++mt2)
            #pragma unroll
            for (int r = 0; r < 4; ++r) {
                const unsigned u = b2w3[mt2 * 4 + r];
                float v = acc2[mt2][r] + bf2f((unsigned short)(u & 0xffffu));
                v = lrelu(v);
                s += v * __uint_as_float(u & 0xffff0000u);
            }
        s += __shfl_xor(s, 16);
        s += __shfl_xor(s, 32);
        if (q == 0) out[e0 + n15] = s + b3v;

        if (!have) break;
        tile = next;
        e0   = next * 16;
        oi = noi; di = ndi; ea = nea; eb = neb;
    }
}

extern "C" void kernel_launch(void* const* d_in, const int* in_sizes, int n_in,
                              void* d_out, int out_size, void* d_ws, size_t ws_size,
                              hipStream_t stream) {
    const float* x   = (const float*)d_in[0];
    const int*   ei  = (const int*)d_in[1];
    const float* ef  = (const float*)d_in[2];
    const float* W1  = (const float*)d_in[3];
    const float* b1  = (const float*)d_in[4];
    const float* W2  = (const float*)d_in[5];
    const float* b2  = (const float*)d_in[6];
    const float* W3  = (const float*)d_in[7];
    const float* b3  = (const float*)d_in[8];
    float*       out = (float*)d_out;

    unsigned short* Pb = (unsigned short*)d_ws;           // [N_NODES][128] bf16 swizzled (+b1)
    unsigned short* Qb = Pb + (size_t)N_NODES * 128;      // [N_NODES][128] bf16 swizzled

    precompute_mfma<<<1024, 256, 0, stream>>>(x, W1, b1, Pb, Qb);
    edge_mfma<<<1024, 256, 0, stream>>>(ei, ef, W1, W2, b2, W3, b3, Pb, Qb, out);
}